// Round 9
// baseline (254.041 us; speedup 1.0000x reference)
//
#include <hip/hip_runtime.h>
#include <stdint.h>

#define N_NODES 100000

// ---------------------------------------------------------------- bf16 helpers
__device__ __forceinline__ unsigned short f2bf(float f){
    uint32_t u = __float_as_uint(f);
    uint32_t r = (u + 0x7FFFu + ((u >> 16) & 1u)) >> 16;   // round-nearest-even
    return (unsigned short)r;
}
__device__ __forceinline__ float bf2f(unsigned short h){
    return __uint_as_float(((uint32_t)h) << 16);
}

// ---------------------------------------------------------------- CSR build
__global__ void zero_u32(uint32_t* p, int n){
    int i = blockIdx.x * 256 + threadIdx.x;
    if (i < n) p[i] = 0u;
}

__global__ void count_dst(const int* __restrict__ dst, uint32_t* __restrict__ cnt, int E){
    int e = blockIdx.x * 256 + threadIdx.x;
    if (e < E) atomicAdd((unsigned int*)&cnt[dst[e]], 1u);
}

__global__ void scan_blocks(const uint32_t* __restrict__ in, uint32_t* __restrict__ out,
                            uint32_t* __restrict__ bsum, int n){
    __shared__ uint32_t tmp[1024];
    int base = blockIdx.x * 1024;
    for (int j = threadIdx.x; j < 1024; j += 256)
        tmp[j] = (base + j < n) ? in[base + j] : 0u;
    __syncthreads();
    for (int off = 1; off < 1024; off <<= 1){
        uint32_t v[4];
        for (int j = 0; j < 4; j++){
            int i = threadIdx.x + j * 256;
            v[j] = (i >= off) ? tmp[i - off] : 0u;
        }
        __syncthreads();
        for (int j = 0; j < 4; j++){
            int i = threadIdx.x + j * 256;
            tmp[i] += v[j];
        }
        __syncthreads();
    }
    for (int j = threadIdx.x; j < 1024; j += 256)
        if (base + j < n) out[base + j] = (j > 0) ? tmp[j - 1] : 0u;
    if (threadIdx.x == 0) bsum[blockIdx.x] = tmp[1023];
}

__global__ void add_boff_dinv(uint32_t* __restrict__ out, const uint32_t* __restrict__ boff,
                              const uint32_t* __restrict__ cnt, float* __restrict__ dinv, int n){
    int base = blockIdx.x * 1024;
    uint32_t add = boff[blockIdx.x];
    for (int j = threadIdx.x; j < 1024; j += 256){
        int i = base + j;
        if (i < n){
            out[i] += add;
            dinv[i] = rsqrtf((float)(cnt[i] + 1u));   // +1 self-loop; always > 0
        }
    }
}

__global__ void fill_csr(const int* __restrict__ src, const int* __restrict__ dst,
                         const uint32_t* __restrict__ off, uint32_t* __restrict__ cur,
                         uint32_t* __restrict__ slot, int E){
    int e = blockIdx.x * 256 + threadIdx.x;
    if (e < E){
        int d = dst[e];
        uint32_t p = atomicAdd((unsigned int*)&cur[d], 1u);
        slot[off[d] + p] = (uint32_t)src[e];
    }
}

// fp32 -> bf16 table conversion (4 elems/thread, coalesced)
__global__ void to_bf16(const float* __restrict__ in, unsigned short* __restrict__ outp, int n4){
    int i = blockIdx.x * 256 + threadIdx.x;
    if (i < n4){
        float4 v = ((const float4*)in)[i];
        ushort4 o = { f2bf(v.x), f2bf(v.y), f2bf(v.z), f2bf(v.w) };
        ((ushort4*)outp)[i] = o;
    }
}

// ---------------------------------------------------------------- aggregation kernel
// OUT[g] = dinv[g] * ( sum_{s in nbr(g)} dinv[s]*X[s] + dinv[g]*X[g] ), bf16 rows.
// No LDS, no barriers -> 8 waves/SIMD of latency hiding. 2 nodes/wave, 32 lanes
// per node (ushort4 = 4 feats each). Index-cache: lane l loads slot[o+l]+dinv
// coalesced; gather loop gets (s,d) via __shfl; groups of 8 load into named
// registers first (8 loads in flight), then convert+FMA. Lanes past rem:
// idx=0, d=0 -> read row 0 (in-bounds, L1-hot), add 0.
__global__ __launch_bounds__(256) void agg_bf(const unsigned short* __restrict__ Xh,
        const uint32_t* __restrict__ offs, const uint32_t* __restrict__ cnt,
        const uint32_t* __restrict__ slot, const float* __restrict__ dinv,
        unsigned short* __restrict__ OUT){
    int wgid = blockIdx.x * 4 + (threadIdx.x >> 6);   // global wave id
    int lane = threadIdx.x & 63;
    int h = lane >> 5, l = lane & 31;
    int g = wgid * 2 + h;                             // node id (grid sized exactly)
    const ushort4* X4 = (const ushort4*)Xh;
    uint32_t o = offs[g], c = cnt[g];
    float ax = 0.f, ay = 0.f, az = 0.f, aw = 0.f;
    #pragma unroll 1
    for (uint32_t base = 0; base < c; base += 32){
        int rem = (int)(c - base); if (rem > 32) rem = 32;
        uint32_t idx = 0u; float ds = 0.f;
        if (l < rem){
            idx = slot[o + base + (uint32_t)l];
            ds = dinv[idx];
        }
        int groups = (rem + 7) >> 3;
        #pragma unroll 1
        for (int gq = 0; gq < groups; gq++){
            int eb = gq * 8;
            ushort4 v[8]; float d[8];
            #pragma unroll
            for (int j = 0; j < 8; j++){
                uint32_t s = (uint32_t)__shfl((int)idx, eb + j, 32);
                d[j] = __shfl(ds, eb + j, 32);
                v[j] = X4[(size_t)s * 32 + l];
            }
            #pragma unroll
            for (int j = 0; j < 8; j++){
                ax += d[j] * bf2f(v[j].x);
                ay += d[j] * bf2f(v[j].y);
                az += d[j] * bf2f(v[j].z);
                aw += d[j] * bf2f(v[j].w);
            }
        }
    }
    float dd = dinv[g];
    ushort4 sv = X4[(size_t)g * 32 + l];
    ushort4 r = { f2bf(dd * (ax + dd * bf2f(sv.x))),
                  f2bf(dd * (ay + dd * bf2f(sv.y))),
                  f2bf(dd * (az + dd * bf2f(sv.z))),
                  f2bf(dd * (aw + dd * bf2f(sv.w))) };
    ((ushort4*)OUT)[(size_t)g * 32 + l] = r;
}

// ---------------------------------------------------------------- tile loader (device helper)
// Load 32 sequential bf16 rows (r0..r0+31) into swizzled fp32 LDS tile xT.
// Wave wid: rows wid*8 .. wid*8+7, 2 rows in parallel (lane halves), lane l
// handles 4 feats. xT word(k,r) = k*32 + 4*((r>>2)^((k>>2)&7)) + (r&3).
__device__ __forceinline__ void load_tile_bf(const unsigned short* __restrict__ Xh,
        float* __restrict__ xT, int r0, int tid){
    int wid = tid >> 6, lane = tid & 63;
    int h = lane >> 5, l = lane & 31;
    const ushort4* X4 = (const ushort4*)Xh;
    #pragma unroll
    for (int i = 0; i < 4; i++){
        int r = wid * 8 + 2 * i + h;
        int g = r0 + r;
        ushort4 v = X4[(size_t)g * 32 + l];
        int sw = (((r >> 2) ^ (l & 7)) << 2) + (r & 3);
        xT[(4 * l + 0) * 32 + sw] = bf2f(v.x);
        xT[(4 * l + 1) * 32 + sw] = bf2f(v.y);
        xT[(4 * l + 2) * 32 + sw] = bf2f(v.z);
        xT[(4 * l + 3) * 32 + sw] = bf2f(v.w);
    }
}

// ---------------------------------------------------------------- GEMM layer 1
// Ah = bf16( relu( Xagg @ W1 + b1 ) ), 32 rows/block, 256 threads, LDS = 32 KiB.
__global__ __launch_bounds__(256) void gemm_l1(const unsigned short* __restrict__ Xagg,
        const float* __restrict__ W, const float* __restrict__ bias,
        unsigned short* __restrict__ OUT){
    __shared__ float Wl[32 * 128];    // 16 KiB (one 32-row K-chunk of W)
    __shared__ float xT[128 * 32];    // 16 KiB, swizzled [k][r]
    int tid = threadIdx.x;
    int r0 = blockIdx.x * 32;

    load_tile_bf(Xagg, xT, r0, tid);

    const float4* W4 = (const float4*)W;    // [128][128] row-major -> 32 float4/row
    float4* Wl4 = (float4*)Wl;
    const float4* xT4 = (const float4*)xT;
    int cg = tid & 31, rg = tid >> 5;
    float4 acc0 = {0,0,0,0}, acc1 = {0,0,0,0}, acc2 = {0,0,0,0}, acc3 = {0,0,0,0};

    #pragma unroll 1
    for (int chunk = 0; chunk < 4; chunk++){
        __syncthreads();                    // xT ready (1st) / prev chunk consumed (rest)
        for (int j = tid; j < 1024; j += 256) Wl4[j] = W4[chunk * 1024 + j];
        __syncthreads();
        #pragma unroll 8
        for (int kk = 0; kk < 32; kk++){
            int k = chunk * 32 + kk;
            float4 w  = Wl4[kk * 32 + cg];
            float4 xv = xT4[k * 8 + (rg ^ ((k >> 2) & 7))];
            acc0.x += xv.x * w.x; acc0.y += xv.x * w.y; acc0.z += xv.x * w.z; acc0.w += xv.x * w.w;
            acc1.x += xv.y * w.x; acc1.y += xv.y * w.y; acc1.z += xv.y * w.z; acc1.w += xv.y * w.w;
            acc2.x += xv.z * w.x; acc2.y += xv.z * w.y; acc2.z += xv.z * w.z; acc2.w += xv.z * w.w;
            acc3.x += xv.w * w.x; acc3.y += xv.w * w.y; acc3.z += xv.w * w.z; acc3.w += xv.w * w.w;
        }
    }

    float4 b = ((const float4*)bias)[cg];
    ushort4* O4 = (ushort4*)OUT;            // 128 bf16/row = 32 ushort4
    int rowbase = r0 + rg * 4;
    ushort4 o0 = { f2bf(fmaxf(acc0.x + b.x, 0.f)), f2bf(fmaxf(acc0.y + b.y, 0.f)),
                   f2bf(fmaxf(acc0.z + b.z, 0.f)), f2bf(fmaxf(acc0.w + b.w, 0.f)) };
    ushort4 o1 = { f2bf(fmaxf(acc1.x + b.x, 0.f)), f2bf(fmaxf(acc1.y + b.y, 0.f)),
                   f2bf(fmaxf(acc1.z + b.z, 0.f)), f2bf(fmaxf(acc1.w + b.w, 0.f)) };
    ushort4 o2 = { f2bf(fmaxf(acc2.x + b.x, 0.f)), f2bf(fmaxf(acc2.y + b.y, 0.f)),
                   f2bf(fmaxf(acc2.z + b.z, 0.f)), f2bf(fmaxf(acc2.w + b.w, 0.f)) };
    ushort4 o3 = { f2bf(fmaxf(acc3.x + b.x, 0.f)), f2bf(fmaxf(acc3.y + b.y, 0.f)),
                   f2bf(fmaxf(acc3.z + b.z, 0.f)), f2bf(fmaxf(acc3.w + b.w, 0.f)) };
    O4[(size_t)(rowbase + 0) * 32 + cg] = o0;
    O4[(size_t)(rowbase + 1) * 32 + cg] = o1;
    O4[(size_t)(rowbase + 2) * 32 + cg] = o2;
    O4[(size_t)(rowbase + 3) * 32 + cg] = o3;
}

// ---------------------------------------------------------------- GEMM layer 2
// out = Aagg @ W2 + b2 (fp32), 32 rows/block, 256 threads, LDS = 26 KiB.
__global__ __launch_bounds__(256) void gemm_l2(const unsigned short* __restrict__ Aagg,
        const float* __restrict__ W, const float* __restrict__ bias,
        float* __restrict__ OUT){
    __shared__ float Wl[64 * 40];     // 10 KiB (one 64-row K-chunk of W2)
    __shared__ float xT[128 * 32];    // 16 KiB, swizzled [k][r]
    int tid = threadIdx.x;
    int r0 = blockIdx.x * 32;

    load_tile_bf(Aagg, xT, r0, tid);

    const float4* W4 = (const float4*)W;   // [128][40] -> 10 float4/row
    float4* Wl4 = (float4*)Wl;
    int r = tid >> 3, cw = tid & 7;        // 32 rows x 8 col-groups (5 cols each)
    int rhi = r >> 2, rlo = r & 3;
    float acc[5] = {0.f, 0.f, 0.f, 0.f, 0.f};

    #pragma unroll 1
    for (int chunk = 0; chunk < 2; chunk++){
        __syncthreads();
        for (int j = tid; j < 640; j += 256) Wl4[j] = W4[chunk * 640 + j];
        __syncthreads();
        #pragma unroll 8
        for (int kk = 0; kk < 64; kk++){
            int k = chunk * 64 + kk;
            float xv = xT[k * 32 + (((rhi ^ ((k >> 2) & 7)) << 2) + rlo)];
            #pragma unroll
            for (int j = 0; j < 5; j++)
                acc[j] += xv * Wl[kk * 40 + 5 * cw + j];
        }
    }
    int g = r0 + r;
    #pragma unroll
    for (int j = 0; j < 5; j++)
        OUT[(size_t)g * 40 + 5 * cw + j] = acc[j] + bias[5 * cw + j];
}

// ---------------------------------------------------------------- launch
extern "C" void kernel_launch(void* const* d_in, const int* in_sizes, int n_in,
                              void* d_out, int out_size, void* d_ws, size_t ws_size,
                              hipStream_t stream) {
    const float* x   = (const float*)d_in[0];
    const int*   ei  = (const int*)d_in[1];      // int32 (harness converts integer inputs)
    const float* W1  = (const float*)d_in[2];
    const float* b1  = (const float*)d_in[3];
    const float* W2  = (const float*)d_in[4];
    const float* b2  = (const float*)d_in[5];
    float*       out = (float*)d_out;

    const int N = N_NODES;
    const int E = in_sizes[1] / 2;
    const int* src = ei;
    const int* dst = ei + E;

    // workspace carve-up (512B-aligned). ~81 MiB total (Xh aliased as Aagg2).
    char* ws = (char*)d_ws;
    size_t o = 0;
    auto alloc = [&](size_t bytes) -> char* {
        char* p = ws + o;
        o += (bytes + 511) & ~(size_t)511;
        return p;
    };
    uint32_t*       cnt   = (uint32_t*)alloc((size_t)N * 4);
    uint32_t*       offs  = (uint32_t*)alloc((size_t)N * 4);
    uint32_t*       cur   = (uint32_t*)alloc((size_t)N * 4);
    uint32_t*       bsum  = (uint32_t*)alloc(1024 * 4);
    uint32_t*       boff  = (uint32_t*)alloc(1024 * 4);
    uint32_t*       bsum2 = (uint32_t*)alloc(512);
    uint32_t*       slot  = (uint32_t*)alloc((size_t)E * 4);
    float*          dinv  = (float*)alloc((size_t)N * 4);
    unsigned short* Xh    = (unsigned short*)alloc((size_t)N * 128 * 2);  // bf16 x; later reused as Aagg2
    unsigned short* Xagg  = (unsigned short*)alloc((size_t)N * 128 * 2);  // aggregated x (bf16)
    unsigned short* Ah    = (unsigned short*)alloc((size_t)N * 128 * 2);  // layer-1 activations (bf16)
    unsigned short* Aagg2 = Xh;   // Xh is dead after agg1; reuse for aggregated activations

    const int zspan = (int)(((char*)cur - (char*)cnt) / 4) + N;  // cnt..cur inclusive
    const int nblk_edges = (E + 255) / 256;       // 2500
    const int nblk_scan  = (N + 1023) / 1024;     // 98
    const int n4 = N * 128 / 4;                   // float4 count for conversion
    const int nblk_agg = N / 8;                   // 12500: 4 waves/block * 2 nodes/wave

    // --- graph structure + bf16 conversion (conversion overlaps CSR chain) ---
    zero_u32<<<(zspan + 255) / 256, 256, 0, stream>>>(cnt, zspan);
    to_bf16<<<(n4 + 255) / 256, 256, 0, stream>>>(x, Xh, n4);
    count_dst<<<nblk_edges, 256, 0, stream>>>(dst, cnt, E);
    scan_blocks<<<nblk_scan, 256, 0, stream>>>(cnt, offs, bsum, N);
    scan_blocks<<<1, 256, 0, stream>>>(bsum, boff, bsum2, nblk_scan);
    add_boff_dinv<<<nblk_scan, 256, 0, stream>>>(offs, boff, cnt, dinv, N);
    fill_csr<<<nblk_edges, 256, 0, stream>>>(src, dst, offs, cur, slot, E);

    // --- layer 1 ---
    agg_bf<<<nblk_agg, 256, 0, stream>>>(Xh, offs, cnt, slot, dinv, Xagg);
    gemm_l1<<<N / 32, 256, 0, stream>>>(Xagg, W1, b1, Ah);

    // --- layer 2 ---
    agg_bf<<<nblk_agg, 256, 0, stream>>>(Ah, offs, cnt, slot, dinv, Aagg2);
    gemm_l2<<<N / 32, 256, 0, stream>>>(Aagg2, W2, b2, out);
}

// Round 10
// 220.251 us; speedup vs baseline: 1.1534x; 1.1534x over previous
//
#include <hip/hip_runtime.h>
#include <stdint.h>

#define N_NODES 100000

typedef __attribute__((ext_vector_type(8))) short bf16x8;   // 8 bf16 = 4 VGPR
typedef __attribute__((ext_vector_type(4))) float f32x4;

// ---------------------------------------------------------------- bf16 helpers
__device__ __forceinline__ unsigned short f2bf(float f){
    uint32_t u = __float_as_uint(f);
    uint32_t r = (u + 0x7FFFu + ((u >> 16) & 1u)) >> 16;   // round-nearest-even
    return (unsigned short)r;
}
__device__ __forceinline__ float bf2f(unsigned short h){
    return __uint_as_float(((uint32_t)h) << 16);
}

// ---------------------------------------------------------------- CSR build
__global__ void zero_u32(uint32_t* p, int n){
    int i = blockIdx.x * 256 + threadIdx.x;
    if (i < n) p[i] = 0u;
}

__global__ void count_dst(const int* __restrict__ dst, uint32_t* __restrict__ cnt, int E){
    int e = blockIdx.x * 256 + threadIdx.x;
    if (e < E) atomicAdd((unsigned int*)&cnt[dst[e]], 1u);
}

__global__ void scan_blocks(const uint32_t* __restrict__ in, uint32_t* __restrict__ out,
                            uint32_t* __restrict__ bsum, int n){
    __shared__ uint32_t tmp[1024];
    int base = blockIdx.x * 1024;
    for (int j = threadIdx.x; j < 1024; j += 256)
        tmp[j] = (base + j < n) ? in[base + j] : 0u;
    __syncthreads();
    for (int off = 1; off < 1024; off <<= 1){
        uint32_t v[4];
        for (int j = 0; j < 4; j++){
            int i = threadIdx.x + j * 256;
            v[j] = (i >= off) ? tmp[i - off] : 0u;
        }
        __syncthreads();
        for (int j = 0; j < 4; j++){
            int i = threadIdx.x + j * 256;
            tmp[i] += v[j];
        }
        __syncthreads();
    }
    for (int j = threadIdx.x; j < 1024; j += 256)
        if (base + j < n) out[base + j] = (j > 0) ? tmp[j - 1] : 0u;
    if (threadIdx.x == 0) bsum[blockIdx.x] = tmp[1023];
}

__global__ void add_boff_dinv(uint32_t* __restrict__ out, const uint32_t* __restrict__ boff,
                              const uint32_t* __restrict__ cnt, float* __restrict__ dinv, int n){
    int base = blockIdx.x * 1024;
    uint32_t add = boff[blockIdx.x];
    for (int j = threadIdx.x; j < 1024; j += 256){
        int i = base + j;
        if (i < n){
            out[i] += add;
            dinv[i] = rsqrtf((float)(cnt[i] + 1u));   // +1 self-loop; always > 0
        }
    }
}

__global__ void fill_csr(const int* __restrict__ src, const int* __restrict__ dst,
                         const uint32_t* __restrict__ off, uint32_t* __restrict__ cur,
                         uint32_t* __restrict__ slot, int E){
    int e = blockIdx.x * 256 + threadIdx.x;
    if (e < E){
        int d = dst[e];
        uint32_t p = atomicAdd((unsigned int*)&cur[d], 1u);
        slot[off[d] + p] = (uint32_t)src[e];
    }
}

// fp32 -> bf16 table conversion (4 elems/thread, coalesced)
__global__ void to_bf16(const float* __restrict__ in, unsigned short* __restrict__ outp, int n4){
    int i = blockIdx.x * 256 + threadIdx.x;
    if (i < n4){
        float4 v = ((const float4*)in)[i];
        ushort4 o = { f2bf(v.x), f2bf(v.y), f2bf(v.z), f2bf(v.w) };
        ((ushort4*)outp)[i] = o;
    }
}

// W [128][NC] fp32 row-major -> Wt [NCpad][128] bf16 (cols >= NC zero-padded).
// i indexes Wt linearly: col = i>>7, k = i&127. Writes coalesced.
__global__ void transpose_w(const float* __restrict__ W, unsigned short* __restrict__ Wt,
                            int NC, int total){
    int i = blockIdx.x * 256 + threadIdx.x;
    if (i < total){
        int col = i >> 7, k = i & 127;
        float v = (col < NC) ? W[(size_t)k * NC + col] : 0.f;
        Wt[i] = f2bf(v);
    }
}

// ---------------------------------------------------------------- aggregation kernel
// OUT[g] = dinv[g] * ( sum_{s in nbr(g)} dinv[s]*X[s] + dinv[g]*X[g] ), bf16 rows.
// No LDS, no barriers -> 8 waves/SIMD latency hiding. 2 nodes/wave, 32 lanes per
// node (ushort4 = 4 feats). Index-cache: lane l loads slot[o+l]+dinv coalesced;
// gather loop gets (s,d) via __shfl; groups of 8 load into named registers first.
__global__ __launch_bounds__(256) void agg_bf(const unsigned short* __restrict__ Xh,
        const uint32_t* __restrict__ offs, const uint32_t* __restrict__ cnt,
        const uint32_t* __restrict__ slot, const float* __restrict__ dinv,
        unsigned short* __restrict__ OUT){
    int wgid = blockIdx.x * 4 + (threadIdx.x >> 6);   // global wave id
    int lane = threadIdx.x & 63;
    int h = lane >> 5, l = lane & 31;
    int g = wgid * 2 + h;                             // node id (grid sized exactly)
    const ushort4* X4 = (const ushort4*)Xh;
    uint32_t o = offs[g], c = cnt[g];
    float ax = 0.f, ay = 0.f, az = 0.f, aw = 0.f;
    #pragma unroll 1
    for (uint32_t base = 0; base < c; base += 32){
        int rem = (int)(c - base); if (rem > 32) rem = 32;
        uint32_t idx = 0u; float ds = 0.f;
        if (l < rem){
            idx = slot[o + base + (uint32_t)l];
            ds = dinv[idx];
        }
        int groups = (rem + 7) >> 3;
        #pragma unroll 1
        for (int gq = 0; gq < groups; gq++){
            int eb = gq * 8;
            ushort4 v[8]; float d[8];
            #pragma unroll
            for (int j = 0; j < 8; j++){
                uint32_t s = (uint32_t)__shfl((int)idx, eb + j, 32);
                d[j] = __shfl(ds, eb + j, 32);
                v[j] = X4[(size_t)s * 32 + l];
            }
            #pragma unroll
            for (int j = 0; j < 8; j++){
                ax += d[j] * bf2f(v[j].x);
                ay += d[j] * bf2f(v[j].y);
                az += d[j] * bf2f(v[j].z);
                aw += d[j] * bf2f(v[j].w);
            }
        }
    }
    float dd = dinv[g];
    ushort4 sv = X4[(size_t)g * 32 + l];
    ushort4 r = { f2bf(dd * (ax + dd * bf2f(sv.x))),
                  f2bf(dd * (ay + dd * bf2f(sv.y))),
                  f2bf(dd * (az + dd * bf2f(sv.z))),
                  f2bf(dd * (aw + dd * bf2f(sv.w))) };
    ((ushort4*)OUT)[(size_t)g * 32 + l] = r;
}

// ---------------------------------------------------------------- MFMA GEMM layer 1
// OUT = bf16( relu( Xagg @ W1 + b1 ) ). 4 waves/block, wave = 32 rows x 128 cols.
// A frag: lane holds Xagg[r0+(l&15)][k0..k0+7] (16B contiguous). B frag: lane
// holds Wt[col][k0..k0+7] = W1[k][col] (16B contiguous). D: col=l&15 (from B),
// row=(l>>4)*4+i. No LDS, no barriers; Wt (32KB) is L1/L2 resident.
__global__ __launch_bounds__(256) void gemm_mfma_l1(const unsigned short* __restrict__ Xagg,
        const unsigned short* __restrict__ Wt, const float* __restrict__ bias,
        unsigned short* __restrict__ OUT){
    int tid = threadIdx.x;
    int wid = tid >> 6, l = tid & 63;
    int lm = l & 15, lk = l >> 4;
    int r0 = blockIdx.x * 128 + wid * 32;
    f32x4 acc0[8] = {}, acc1[8] = {};

    int ra = r0 + lm;      ra = ra < N_NODES ? ra : N_NODES - 1;
    int rb = r0 + 16 + lm; rb = rb < N_NODES ? rb : N_NODES - 1;
    #pragma unroll
    for (int step = 0; step < 4; step++){
        int k0 = step * 32 + lk * 8;
        bf16x8 a0 = *(const bf16x8*)(Xagg + (size_t)ra * 128 + k0);
        bf16x8 a1 = *(const bf16x8*)(Xagg + (size_t)rb * 128 + k0);
        #pragma unroll
        for (int cb = 0; cb < 8; cb++){
            bf16x8 b = *(const bf16x8*)(Wt + (size_t)(cb * 16 + lm) * 128 + k0);
            acc0[cb] = __builtin_amdgcn_mfma_f32_16x16x32_bf16(a0, b, acc0[cb], 0, 0, 0);
            acc1[cb] = __builtin_amdgcn_mfma_f32_16x16x32_bf16(a1, b, acc1[cb], 0, 0, 0);
        }
    }
    #pragma unroll
    for (int cb = 0; cb < 8; cb++){
        int col = cb * 16 + lm;
        float bs = bias[col];
        #pragma unroll
        for (int i = 0; i < 4; i++){
            int row0 = r0 + lk * 4 + i;
            int row1 = r0 + 16 + lk * 4 + i;
            if (row0 < N_NODES)
                OUT[(size_t)row0 * 128 + col] = f2bf(fmaxf(acc0[cb][i] + bs, 0.f));
            if (row1 < N_NODES)
                OUT[(size_t)row1 * 128 + col] = f2bf(fmaxf(acc1[cb][i] + bs, 0.f));
        }
    }
}

// ---------------------------------------------------------------- MFMA GEMM layer 2
// OUT = Aagg @ W2 + b2 (fp32, 40 cols; Wt2 padded to 48 cols with zeros).
__global__ __launch_bounds__(256) void gemm_mfma_l2(const unsigned short* __restrict__ Aagg,
        const unsigned short* __restrict__ Wt, const float* __restrict__ bias,
        float* __restrict__ OUT){
    int tid = threadIdx.x;
    int wid = tid >> 6, l = tid & 63;
    int lm = l & 15, lk = l >> 4;
    int r0 = blockIdx.x * 128 + wid * 32;
    f32x4 acc0[3] = {}, acc1[3] = {};

    int ra = r0 + lm;      ra = ra < N_NODES ? ra : N_NODES - 1;
    int rb = r0 + 16 + lm; rb = rb < N_NODES ? rb : N_NODES - 1;
    #pragma unroll
    for (int step = 0; step < 4; step++){
        int k0 = step * 32 + lk * 8;
        bf16x8 a0 = *(const bf16x8*)(Aagg + (size_t)ra * 128 + k0);
        bf16x8 a1 = *(const bf16x8*)(Aagg + (size_t)rb * 128 + k0);
        #pragma unroll
        for (int cb = 0; cb < 3; cb++){
            bf16x8 b = *(const bf16x8*)(Wt + (size_t)(cb * 16 + lm) * 128 + k0);
            acc0[cb] = __builtin_amdgcn_mfma_f32_16x16x32_bf16(a0, b, acc0[cb], 0, 0, 0);
            acc1[cb] = __builtin_amdgcn_mfma_f32_16x16x32_bf16(a1, b, acc1[cb], 0, 0, 0);
        }
    }
    #pragma unroll
    for (int cb = 0; cb < 3; cb++){
        int col = cb * 16 + lm;
        if (col < 40){
            float bs = bias[col];
            #pragma unroll
            for (int i = 0; i < 4; i++){
                int row0 = r0 + lk * 4 + i;
                int row1 = r0 + 16 + lk * 4 + i;
                if (row0 < N_NODES) OUT[(size_t)row0 * 40 + col] = acc0[cb][i] + bs;
                if (row1 < N_NODES) OUT[(size_t)row1 * 40 + col] = acc1[cb][i] + bs;
            }
        }
    }
}

// ---------------------------------------------------------------- launch
extern "C" void kernel_launch(void* const* d_in, const int* in_sizes, int n_in,
                              void* d_out, int out_size, void* d_ws, size_t ws_size,
                              hipStream_t stream) {
    const float* x   = (const float*)d_in[0];
    const int*   ei  = (const int*)d_in[1];      // int32 (harness converts integer inputs)
    const float* W1  = (const float*)d_in[2];
    const float* b1  = (const float*)d_in[3];
    const float* W2  = (const float*)d_in[4];
    const float* b2  = (const float*)d_in[5];
    float*       out = (float*)d_out;

    const int N = N_NODES;
    const int E = in_sizes[1] / 2;
    const int* src = ei;
    const int* dst = ei + E;

    // workspace carve-up (512B-aligned). ~81 MiB total (Xh aliased as Aagg2).
    char* ws = (char*)d_ws;
    size_t o = 0;
    auto alloc = [&](size_t bytes) -> char* {
        char* p = ws + o;
        o += (bytes + 511) & ~(size_t)511;
        return p;
    };
    uint32_t*       cnt   = (uint32_t*)alloc((size_t)N * 4);
    uint32_t*       offs  = (uint32_t*)alloc((size_t)N * 4);
    uint32_t*       cur   = (uint32_t*)alloc((size_t)N * 4);
    uint32_t*       bsum  = (uint32_t*)alloc(1024 * 4);
    uint32_t*       boff  = (uint32_t*)alloc(1024 * 4);
    uint32_t*       bsum2 = (uint32_t*)alloc(512);
    uint32_t*       slot  = (uint32_t*)alloc((size_t)E * 4);
    float*          dinv  = (float*)alloc((size_t)N * 4);
    unsigned short* Wt1   = (unsigned short*)alloc((size_t)128 * 128 * 2);  // W1^T bf16
    unsigned short* Wt2   = (unsigned short*)alloc((size_t)48 * 128 * 2);   // W2^T bf16 (padded)
    unsigned short* Xh    = (unsigned short*)alloc((size_t)N * 128 * 2);  // bf16 x; later Aagg2
    unsigned short* Xagg  = (unsigned short*)alloc((size_t)N * 128 * 2);  // aggregated x (bf16)
    unsigned short* Ah    = (unsigned short*)alloc((size_t)N * 128 * 2);  // layer-1 act (bf16)
    unsigned short* Aagg2 = Xh;   // Xh dead after agg1; reuse

    const int zspan = (int)(((char*)cur - (char*)cnt) / 4) + N;  // cnt..cur inclusive
    const int nblk_edges = (E + 255) / 256;       // 2500
    const int nblk_scan  = (N + 1023) / 1024;     // 98
    const int n4 = N * 128 / 4;
    const int nblk_agg = N / 8;                   // 12500
    const int nblk_gemm = (N + 127) / 128;        // 782

    // --- graph structure + bf16 conversions (overlap the CSR chain) ---
    zero_u32<<<(zspan + 255) / 256, 256, 0, stream>>>(cnt, zspan);
    to_bf16<<<(n4 + 255) / 256, 256, 0, stream>>>(x, Xh, n4);
    transpose_w<<<64, 256, 0, stream>>>(W1, Wt1, 128, 128 * 128);
    transpose_w<<<24, 256, 0, stream>>>(W2, Wt2, 40, 48 * 128);
    count_dst<<<nblk_edges, 256, 0, stream>>>(dst, cnt, E);
    scan_blocks<<<nblk_scan, 256, 0, stream>>>(cnt, offs, bsum, N);
    scan_blocks<<<1, 256, 0, stream>>>(bsum, boff, bsum2, nblk_scan);
    add_boff_dinv<<<nblk_scan, 256, 0, stream>>>(offs, boff, cnt, dinv, N);
    fill_csr<<<nblk_edges, 256, 0, stream>>>(src, dst, offs, cur, slot, E);

    // --- layer 1 ---
    agg_bf<<<nblk_agg, 256, 0, stream>>>(Xh, offs, cnt, slot, dinv, Xagg);
    gemm_mfma_l1<<<nblk_gemm, 256, 0, stream>>>(Xagg, Wt1, b1, Ah);

    // --- layer 2 ---
    agg_bf<<<nblk_agg, 256, 0, stream>>>(Ah, offs, cnt, slot, dinv, Aagg2);
    gemm_mfma_l2<<<nblk_gemm, 256, 0, stream>>>(Aagg2, Wt2, b2, out);
}

// Round 11
// 193.051 us; speedup vs baseline: 1.3159x; 1.1409x over previous
//
#include <hip/hip_runtime.h>
#include <stdint.h>

#define N_NODES 100000

typedef __attribute__((ext_vector_type(8))) short bf16x8;   // 8 bf16 = 4 VGPR
typedef __attribute__((ext_vector_type(4))) float f32x4;

// ---------------------------------------------------------------- bf16 helpers
__device__ __forceinline__ unsigned short f2bf(float f){
    uint32_t u = __float_as_uint(f);
    uint32_t r = (u + 0x7FFFu + ((u >> 16) & 1u)) >> 16;   // round-nearest-even
    return (unsigned short)r;
}
__device__ __forceinline__ float bf2f(unsigned short h){
    return __uint_as_float(((uint32_t)h) << 16);
}

// ---------------------------------------------------------------- CSR build
__global__ void zero_u32(uint32_t* p, int n){
    int i = blockIdx.x * 256 + threadIdx.x;
    if (i < n) p[i] = 0u;
}

__global__ void count_dst(const int* __restrict__ dst, uint32_t* __restrict__ cnt, int E){
    int e = blockIdx.x * 256 + threadIdx.x;
    if (e < E) atomicAdd((unsigned int*)&cnt[dst[e]], 1u);
}

__global__ void scan_blocks(const uint32_t* __restrict__ in, uint32_t* __restrict__ out,
                            uint32_t* __restrict__ bsum, int n){
    __shared__ uint32_t tmp[1024];
    int base = blockIdx.x * 1024;
    for (int j = threadIdx.x; j < 1024; j += 256)
        tmp[j] = (base + j < n) ? in[base + j] : 0u;
    __syncthreads();
    for (int off = 1; off < 1024; off <<= 1){
        uint32_t v[4];
        for (int j = 0; j < 4; j++){
            int i = threadIdx.x + j * 256;
            v[j] = (i >= off) ? tmp[i - off] : 0u;
        }
        __syncthreads();
        for (int j = 0; j < 4; j++){
            int i = threadIdx.x + j * 256;
            tmp[i] += v[j];
        }
        __syncthreads();
    }
    for (int j = threadIdx.x; j < 1024; j += 256)
        if (base + j < n) out[base + j] = (j > 0) ? tmp[j - 1] : 0u;
    if (threadIdx.x == 0) bsum[blockIdx.x] = tmp[1023];
}

__global__ void add_boff_dinv(uint32_t* __restrict__ out, const uint32_t* __restrict__ boff,
                              const uint32_t* __restrict__ cnt, float* __restrict__ dinv, int n){
    int base = blockIdx.x * 1024;
    uint32_t add = boff[blockIdx.x];
    for (int j = threadIdx.x; j < 1024; j += 256){
        int i = base + j;
        if (i < n){
            out[i] += add;
            dinv[i] = rsqrtf((float)(cnt[i] + 1u));   // +1 self-loop; always > 0
        }
    }
}

__global__ void fill_csr(const int* __restrict__ src, const int* __restrict__ dst,
                         const uint32_t* __restrict__ off, uint32_t* __restrict__ cur,
                         uint32_t* __restrict__ slot, int E){
    int e = blockIdx.x * 256 + threadIdx.x;
    if (e < E){
        int d = dst[e];
        uint32_t p = atomicAdd((unsigned int*)&cur[d], 1u);
        slot[off[d] + p] = (uint32_t)src[e];
    }
}

// fp32 -> bf16 table conversion (4 elems/thread, coalesced)
__global__ void to_bf16(const float* __restrict__ in, unsigned short* __restrict__ outp, int n4){
    int i = blockIdx.x * 256 + threadIdx.x;
    if (i < n4){
        float4 v = ((const float4*)in)[i];
        ushort4 o = { f2bf(v.x), f2bf(v.y), f2bf(v.z), f2bf(v.w) };
        ((ushort4*)outp)[i] = o;
    }
}

// W [128][NC] fp32 row-major -> fragment-order bf16 table:
// Wtf[((cb*4+step)*64 + lane)*8 + j] = W[step*32 + (lane>>4)*8 + j][cb*16 + (lane&15)]
// so a wave's B-fragment load for (cb,step) is ONE coalesced 1KB read.
__global__ void transpose_w_frag(const float* __restrict__ W, unsigned short* __restrict__ Wtf,
                                 int NC, int total){
    int i = blockIdx.x * 256 + threadIdx.x;
    if (i < total){
        int j  = i & 7;
        int l  = (i >> 3) & 63;
        int st = (i >> 9) & 3;
        int cb = i >> 11;
        int k   = st * 32 + (l >> 4) * 8 + j;
        int col = cb * 16 + (l & 15);
        float v = (col < NC) ? W[(size_t)k * NC + col] : 0.f;
        Wtf[i] = f2bf(v);
    }
}

// ---------------------------------------------------------------- aggregation kernel
// OUT[g] = dinv[g] * ( sum_{s in nbr(g)} dinv[s]*X[s] + dinv[g]*X[g] ), bf16 rows.
// No LDS, no barriers -> 8 waves/SIMD latency hiding. 2 nodes/wave, 32 lanes per
// node (ushort4 = 4 feats). Index-cache: lane l loads slot[o+l]+dinv coalesced;
// gather loop gets (s,d) via __shfl; groups of 8 load into named registers first.
__global__ __launch_bounds__(256) void agg_bf(const unsigned short* __restrict__ Xh,
        const uint32_t* __restrict__ offs, const uint32_t* __restrict__ cnt,
        const uint32_t* __restrict__ slot, const float* __restrict__ dinv,
        unsigned short* __restrict__ OUT){
    int wgid = blockIdx.x * 4 + (threadIdx.x >> 6);   // global wave id
    int lane = threadIdx.x & 63;
    int h = lane >> 5, l = lane & 31;
    int g = wgid * 2 + h;                             // node id (grid sized exactly)
    const ushort4* X4 = (const ushort4*)Xh;
    uint32_t o = offs[g], c = cnt[g];
    float ax = 0.f, ay = 0.f, az = 0.f, aw = 0.f;
    #pragma unroll 1
    for (uint32_t base = 0; base < c; base += 32){
        int rem = (int)(c - base); if (rem > 32) rem = 32;
        uint32_t idx = 0u; float ds = 0.f;
        if (l < rem){
            idx = slot[o + base + (uint32_t)l];
            ds = dinv[idx];
        }
        int groups = (rem + 7) >> 3;
        #pragma unroll 1
        for (int gq = 0; gq < groups; gq++){
            int eb = gq * 8;
            ushort4 v[8]; float d[8];
            #pragma unroll
            for (int j = 0; j < 8; j++){
                uint32_t s = (uint32_t)__shfl((int)idx, eb + j, 32);
                d[j] = __shfl(ds, eb + j, 32);
                v[j] = X4[(size_t)s * 32 + l];
            }
            #pragma unroll
            for (int j = 0; j < 8; j++){
                ax += d[j] * bf2f(v[j].x);
                ay += d[j] * bf2f(v[j].y);
                az += d[j] * bf2f(v[j].z);
                aw += d[j] * bf2f(v[j].w);
            }
        }
    }
    float dd = dinv[g];
    ushort4 sv = X4[(size_t)g * 32 + l];
    ushort4 r = { f2bf(dd * (ax + dd * bf2f(sv.x))),
                  f2bf(dd * (ay + dd * bf2f(sv.y))),
                  f2bf(dd * (az + dd * bf2f(sv.z))),
                  f2bf(dd * (aw + dd * bf2f(sv.w))) };
    ((ushort4*)OUT)[(size_t)g * 32 + l] = r;
}

// ---------------------------------------------------------------- MFMA GEMM layer 1
// OUT = bf16( relu( Xagg @ W1 + b1 ) ). 4 waves/block, wave = 16 rows x 128 cols.
// A frag: lane (lm,lk) holds Xagg[rw+lm][step*32+lk*8 ..+7] (16B). B frag: one
// coalesced 1KB load from fragment-order Wtf. Software pipeline: step s+1 frags
// load into the alternate named bank during step s's MFMAs.
__global__ __launch_bounds__(256) void gemm_mfma_l1(const unsigned short* __restrict__ Xagg,
        const unsigned short* __restrict__ Wtf, const float* __restrict__ bias,
        unsigned short* __restrict__ OUT){
    int tid = threadIdx.x;
    int wid = tid >> 6, l = tid & 63;
    int lm = l & 15, lk = l >> 4;
    int rw = blockIdx.x * 64 + wid * 16;            // wave's first row
    int ra = rw + lm; ra = ra < N_NODES ? ra : N_NODES - 1;
    const bf16x8* Wv = (const bf16x8*)Wtf;          // frag index = (cb*4+step)*64 + l

    f32x4 acc[8] = {};
    bf16x8 aA, aB, bA[8], bB[8];

    // prologue: step 0 into bank A
    aA = *(const bf16x8*)(Xagg + (size_t)ra * 128 + lk * 8);
    #pragma unroll
    for (int cb = 0; cb < 8; cb++) bA[cb] = Wv[(size_t)(cb * 4 + 0) * 64 + l];

    // step 0: prefetch 1 into B, compute A
    aB = *(const bf16x8*)(Xagg + (size_t)ra * 128 + 32 + lk * 8);
    #pragma unroll
    for (int cb = 0; cb < 8; cb++) bB[cb] = Wv[(size_t)(cb * 4 + 1) * 64 + l];
    #pragma unroll
    for (int cb = 0; cb < 8; cb++)
        acc[cb] = __builtin_amdgcn_mfma_f32_16x16x32_bf16(aA, bA[cb], acc[cb], 0, 0, 0);

    // step 1: prefetch 2 into A, compute B
    aA = *(const bf16x8*)(Xagg + (size_t)ra * 128 + 64 + lk * 8);
    #pragma unroll
    for (int cb = 0; cb < 8; cb++) bA[cb] = Wv[(size_t)(cb * 4 + 2) * 64 + l];
    #pragma unroll
    for (int cb = 0; cb < 8; cb++)
        acc[cb] = __builtin_amdgcn_mfma_f32_16x16x32_bf16(aB, bB[cb], acc[cb], 0, 0, 0);

    // step 2: prefetch 3 into B, compute A
    aB = *(const bf16x8*)(Xagg + (size_t)ra * 128 + 96 + lk * 8);
    #pragma unroll
    for (int cb = 0; cb < 8; cb++) bB[cb] = Wv[(size_t)(cb * 4 + 3) * 64 + l];
    #pragma unroll
    for (int cb = 0; cb < 8; cb++)
        acc[cb] = __builtin_amdgcn_mfma_f32_16x16x32_bf16(aA, bA[cb], acc[cb], 0, 0, 0);

    // step 3: compute B
    #pragma unroll
    for (int cb = 0; cb < 8; cb++)
        acc[cb] = __builtin_amdgcn_mfma_f32_16x16x32_bf16(aB, bB[cb], acc[cb], 0, 0, 0);

    #pragma unroll
    for (int cb = 0; cb < 8; cb++){
        int col = cb * 16 + lm;
        float bs = bias[col];
        #pragma unroll
        for (int i = 0; i < 4; i++){
            int row = rw + lk * 4 + i;
            if (row < N_NODES)
                OUT[(size_t)row * 128 + col] = f2bf(fmaxf(acc[cb][i] + bs, 0.f));
        }
    }
}

// ---------------------------------------------------------------- MFMA GEMM layer 2
// OUT = Aagg @ W2 + b2 (fp32, 40 cols; Wtf2 padded to 48 cols with zeros).
__global__ __launch_bounds__(256) void gemm_mfma_l2(const unsigned short* __restrict__ Aagg,
        const unsigned short* __restrict__ Wtf, const float* __restrict__ bias,
        float* __restrict__ OUT){
    int tid = threadIdx.x;
    int wid = tid >> 6, l = tid & 63;
    int lm = l & 15, lk = l >> 4;
    int rw = blockIdx.x * 64 + wid * 16;
    int ra = rw + lm; ra = ra < N_NODES ? ra : N_NODES - 1;
    const bf16x8* Wv = (const bf16x8*)Wtf;

    f32x4 acc[3] = {};
    bf16x8 aA, aB, bA[3], bB[3];

    aA = *(const bf16x8*)(Aagg + (size_t)ra * 128 + lk * 8);
    #pragma unroll
    for (int cb = 0; cb < 3; cb++) bA[cb] = Wv[(size_t)(cb * 4 + 0) * 64 + l];

    aB = *(const bf16x8*)(Aagg + (size_t)ra * 128 + 32 + lk * 8);
    #pragma unroll
    for (int cb = 0; cb < 3; cb++) bB[cb] = Wv[(size_t)(cb * 4 + 1) * 64 + l];
    #pragma unroll
    for (int cb = 0; cb < 3; cb++)
        acc[cb] = __builtin_amdgcn_mfma_f32_16x16x32_bf16(aA, bA[cb], acc[cb], 0, 0, 0);

    aA = *(const bf16x8*)(Aagg + (size_t)ra * 128 + 64 + lk * 8);
    #pragma unroll
    for (int cb = 0; cb < 3; cb++) bA[cb] = Wv[(size_t)(cb * 4 + 2) * 64 + l];
    #pragma unroll
    for (int cb = 0; cb < 3; cb++)
        acc[cb] = __builtin_amdgcn_mfma_f32_16x16x32_bf16(aB, bB[cb], acc[cb], 0, 0, 0);

    aB = *(const bf16x8*)(Aagg + (size_t)ra * 128 + 96 + lk * 8);
    #pragma unroll
    for (int cb = 0; cb < 3; cb++) bB[cb] = Wv[(size_t)(cb * 4 + 3) * 64 + l];
    #pragma unroll
    for (int cb = 0; cb < 3; cb++)
        acc[cb] = __builtin_amdgcn_mfma_f32_16x16x32_bf16(aA, bA[cb], acc[cb], 0, 0, 0);

    #pragma unroll
    for (int cb = 0; cb < 3; cb++)
        acc[cb] = __builtin_amdgcn_mfma_f32_16x16x32_bf16(aB, bB[cb], acc[cb], 0, 0, 0);

    #pragma unroll
    for (int cb = 0; cb < 3; cb++){
        int col = cb * 16 + lm;
        if (col < 40){
            float bs = bias[col];
            #pragma unroll
            for (int i = 0; i < 4; i++){
                int row = rw + lk * 4 + i;
                if (row < N_NODES) OUT[(size_t)row * 40 + col] = acc[cb][i] + bs;
            }
        }
    }
}

// ---------------------------------------------------------------- launch
extern "C" void kernel_launch(void* const* d_in, const int* in_sizes, int n_in,
                              void* d_out, int out_size, void* d_ws, size_t ws_size,
                              hipStream_t stream) {
    const float* x   = (const float*)d_in[0];
    const int*   ei  = (const int*)d_in[1];      // int32 (harness converts integer inputs)
    const float* W1  = (const float*)d_in[2];
    const float* b1  = (const float*)d_in[3];
    const float* W2  = (const float*)d_in[4];
    const float* b2  = (const float*)d_in[5];
    float*       out = (float*)d_out;

    const int N = N_NODES;
    const int E = in_sizes[1] / 2;
    const int* src = ei;
    const int* dst = ei + E;

    // workspace carve-up (512B-aligned). ~81 MiB total (Xh aliased as Aagg2).
    char* ws = (char*)d_ws;
    size_t o = 0;
    auto alloc = [&](size_t bytes) -> char* {
        char* p = ws + o;
        o += (bytes + 511) & ~(size_t)511;
        return p;
    };
    uint32_t*       cnt   = (uint32_t*)alloc((size_t)N * 4);
    uint32_t*       offs  = (uint32_t*)alloc((size_t)N * 4);
    uint32_t*       cur   = (uint32_t*)alloc((size_t)N * 4);
    uint32_t*       bsum  = (uint32_t*)alloc(1024 * 4);
    uint32_t*       boff  = (uint32_t*)alloc(1024 * 4);
    uint32_t*       bsum2 = (uint32_t*)alloc(512);
    uint32_t*       slot  = (uint32_t*)alloc((size_t)E * 4);
    float*          dinv  = (float*)alloc((size_t)N * 4);
    unsigned short* Wtf1  = (unsigned short*)alloc((size_t)8 * 4 * 64 * 8 * 2);  // 32 KB
    unsigned short* Wtf2  = (unsigned short*)alloc((size_t)3 * 4 * 64 * 8 * 2);  // 12 KB
    unsigned short* Xh    = (unsigned short*)alloc((size_t)N * 128 * 2);  // bf16 x; later Aagg2
    unsigned short* Xagg  = (unsigned short*)alloc((size_t)N * 128 * 2);  // aggregated x (bf16)
    unsigned short* Ah    = (unsigned short*)alloc((size_t)N * 128 * 2);  // layer-1 act (bf16)
    unsigned short* Aagg2 = Xh;   // Xh dead after agg1; reuse

    const int zspan = (int)(((char*)cur - (char*)cnt) / 4) + N;  // cnt..cur inclusive
    const int nblk_edges = (E + 255) / 256;       // 2500
    const int nblk_scan  = (N + 1023) / 1024;     // 98
    const int n4 = N * 128 / 4;
    const int nblk_agg = N / 8;                   // 12500
    const int nblk_gemm = (N + 63) / 64;          // 1563

    // --- graph structure + bf16 conversions (overlap the CSR chain) ---
    zero_u32<<<(zspan + 255) / 256, 256, 0, stream>>>(cnt, zspan);
    to_bf16<<<(n4 + 255) / 256, 256, 0, stream>>>(x, Xh, n4);
    transpose_w_frag<<<64, 256, 0, stream>>>(W1, Wtf1, 128, 8 * 4 * 64 * 8);
    transpose_w_frag<<<24, 256, 0, stream>>>(W2, Wtf2, 40, 3 * 4 * 64 * 8);
    count_dst<<<nblk_edges, 256, 0, stream>>>(dst, cnt, E);
    scan_blocks<<<nblk_scan, 256, 0, stream>>>(cnt, offs, bsum, N);
    scan_blocks<<<1, 256, 0, stream>>>(bsum, boff, bsum2, nblk_scan);
    add_boff_dinv<<<nblk_scan, 256, 0, stream>>>(offs, boff, cnt, dinv, N);
    fill_csr<<<nblk_edges, 256, 0, stream>>>(src, dst, offs, cur, slot, E);

    // --- layer 1 ---
    agg_bf<<<nblk_agg, 256, 0, stream>>>(Xh, offs, cnt, slot, dinv, Xagg);
    gemm_mfma_l1<<<nblk_gemm, 256, 0, stream>>>(Xagg, Wtf1, b1, Ah);

    // --- layer 2 ---
    agg_bf<<<nblk_agg, 256, 0, stream>>>(Ah, offs, cnt, slot, dinv, Aagg2);
    gemm_mfma_l2<<<nblk_gemm, 256, 0, stream>>>(Aagg2, Wtf2, b2, out);
}

// Round 12
// 157.071 us; speedup vs baseline: 1.6174x; 1.2291x over previous
//
#include <hip/hip_runtime.h>
#include <stdint.h>

#define N_NODES 100000
#define NB 782            // (N_NODES + 127) >> 7  buckets of 128 nodes
#define NBP 784           // padded
#define BCAP 1536         // max edges per bucket (mean 819, sd 28.6 -> 25 sigma)

typedef __attribute__((ext_vector_type(8))) short bf16x8;   // 8 bf16 = 4 VGPR
typedef __attribute__((ext_vector_type(4))) float f32x4;

// ---------------------------------------------------------------- bf16 helpers
__device__ __forceinline__ unsigned short f2bf(float f){
    uint32_t u = __float_as_uint(f);
    uint32_t r = (u + 0x7FFFu + ((u >> 16) & 1u)) >> 16;   // round-nearest-even
    return (unsigned short)r;
}
__device__ __forceinline__ float bf2f(unsigned short h){
    return __uint_as_float(((uint32_t)h) << 16);
}

// ---------------------------------------------------------------- misc
__global__ void zero_u32(uint32_t* p, int n){
    int i = blockIdx.x * 256 + threadIdx.x;
    if (i < n) p[i] = 0u;
}

// fp32 -> bf16 table conversion (4 elems/thread, coalesced)
__global__ void to_bf16(const float* __restrict__ in, unsigned short* __restrict__ outp, int n4){
    int i = blockIdx.x * 256 + threadIdx.x;
    if (i < n4){
        float4 v = ((const float4*)in)[i];
        ushort4 o = { f2bf(v.x), f2bf(v.y), f2bf(v.z), f2bf(v.w) };
        ((ushort4*)outp)[i] = o;
    }
}

// W [128][NC] fp32 row-major -> fragment-order bf16 table:
// Wtf[((cb*4+step)*64 + lane)*8 + j] = W[step*32 + (lane>>4)*8 + j][cb*16 + (lane&15)]
__global__ void transpose_w_frag(const float* __restrict__ W, unsigned short* __restrict__ Wtf,
                                 int NC, int total){
    int i = blockIdx.x * 256 + threadIdx.x;
    if (i < total){
        int j  = i & 7;
        int l  = (i >> 3) & 63;
        int st = (i >> 9) & 3;
        int cb = i >> 11;
        int k   = st * 32 + (l >> 4) * 8 + j;
        int col = cb * 16 + (l & 15);
        float v = (col < NC) ? W[(size_t)k * NC + col] : 0.f;
        Wtf[i] = f2bf(v);
    }
}

// ---------------------------------------------------------------- bucketed CSR build
// P1: per-block LDS histogram of dst>>7, flushed with one atomic per bucket.
__global__ __launch_bounds__(1024) void bucket_hist(const int* __restrict__ dst,
        uint32_t* __restrict__ hist, int E){
    __shared__ uint32_t h[NBP];
    for (int i = threadIdx.x; i < NB; i += 1024) h[i] = 0u;
    __syncthreads();
    int base = blockIdx.x * 12800;
    for (int i = threadIdx.x; i < 12800; i += 1024){
        int e = base + i;
        if (e < E) atomicAdd(&h[(uint32_t)dst[e] >> 7], 1u);
    }
    __syncthreads();
    for (int i = threadIdx.x; i < NB; i += 1024)
        if (h[i]) atomicAdd(&hist[i], h[i]);
}

// P2: exclusive scan of hist -> base; cur = base (one block).
__global__ void scan_buckets(const uint32_t* __restrict__ hist,
                             uint32_t* __restrict__ base, uint32_t* __restrict__ cur){
    __shared__ uint32_t tmp[1024];
    int t = threadIdx.x;
    for (int j = t; j < 1024; j += 256) tmp[j] = (j < NB) ? hist[j] : 0u;
    __syncthreads();
    for (int off = 1; off < 1024; off <<= 1){
        uint32_t v[4];
        for (int j = 0; j < 4; j++){
            int i = t + j * 256;
            v[j] = (i >= off) ? tmp[i - off] : 0u;
        }
        __syncthreads();
        for (int j = 0; j < 4; j++) tmp[t + j * 256] += v[j];
        __syncthreads();
    }
    for (int j = t; j < NB; j += 256){
        uint32_t v = (j > 0) ? tmp[j - 1] : 0u;
        base[j] = v;
        cur[j] = v;
    }
}

// P3: scatter packed edges into bucket-sorted ebuf. Block reserves space per
// bucket with ONE atomic, ranks edges via LDS atomics -> dense writes.
// packed = (dst & 127) << 17 | src   (src < 2^17, local-d 7 bits)
__global__ __launch_bounds__(1024) void bucket_scatter(const int* __restrict__ src,
        const int* __restrict__ dst, uint32_t* __restrict__ cur,
        uint32_t* __restrict__ ebuf, int E){
    __shared__ uint32_t h[NBP];
    __shared__ uint32_t st[NBP];
    for (int i = threadIdx.x; i < NB; i += 1024) h[i] = 0u;
    __syncthreads();
    int base = blockIdx.x * 12800;
    for (int i = threadIdx.x; i < 12800; i += 1024){
        int e = base + i;
        if (e < E) atomicAdd(&h[(uint32_t)dst[e] >> 7], 1u);
    }
    __syncthreads();
    for (int i = threadIdx.x; i < NB; i += 1024){
        uint32_t c = h[i];
        st[i] = c ? atomicAdd(&cur[i], c) : 0u;
        h[i] = 0u;                       // reuse as rank counter
    }
    __syncthreads();
    for (int i = threadIdx.x; i < 12800; i += 1024){
        int e = base + i;
        if (e < E){
            uint32_t d = (uint32_t)dst[e];
            uint32_t b = d >> 7;
            uint32_t r = atomicAdd(&h[b], 1u);
            ebuf[st[b] + r] = ((d & 127u) << 17) | (uint32_t)src[e];
        }
    }
}

// P4: per bucket (128 nodes): LDS count -> LDS scan -> offs/cnt/dinv (dense),
// then rank edges per node -> slot within the bucket's contiguous region.
__global__ __launch_bounds__(256) void bucket_csr(const uint32_t* __restrict__ hist,
        const uint32_t* __restrict__ base, const uint32_t* __restrict__ ebuf,
        uint32_t* __restrict__ offs, uint32_t* __restrict__ cnt, float* __restrict__ dinv,
        uint32_t* __restrict__ slot, int N){
    __shared__ uint32_t ebl[BCAP];
    __shared__ uint32_t ncnt[128], loff[128], ncur[128], stmp[128];
    int b = blockIdx.x, t = threadIdx.x;
    uint32_t eb = base[b], ec = hist[b];
    if (ec > BCAP) ec = BCAP;            // unreachable safety
    for (uint32_t i = t; i < ec; i += 256) ebl[i] = ebuf[eb + i];
    if (t < 128){ ncnt[t] = 0u; ncur[t] = 0u; }
    __syncthreads();
    for (uint32_t i = t; i < ec; i += 256) atomicAdd(&ncnt[ebl[i] >> 17], 1u);
    __syncthreads();
    if (t < 128) stmp[t] = ncnt[t];
    __syncthreads();
    for (int off = 1; off < 128; off <<= 1){
        uint32_t v = 0u;
        if (t < 128 && t >= off) v = stmp[t - off];
        __syncthreads();
        if (t < 128) stmp[t] += v;
        __syncthreads();
    }
    if (t < 128) loff[t] = stmp[t] - ncnt[t];    // inclusive -> exclusive
    __syncthreads();
    int g = b * 128 + t;
    if (t < 128 && g < N){
        offs[g] = eb + loff[t];
        cnt[g]  = ncnt[t];
        dinv[g] = rsqrtf((float)(ncnt[t] + 1u));
    }
    for (uint32_t i = t; i < ec; i += 256){
        uint32_t p  = ebl[i];
        uint32_t ld = p >> 17;
        uint32_t r  = atomicAdd(&ncur[ld], 1u);
        slot[eb + loff[ld] + r] = p & 0x1FFFFu;
    }
}

// ---------------------------------------------------------------- aggregation kernel
// OUT[g] = dinv[g] * ( sum_{s in nbr(g)} dinv[s]*X[s] + dinv[g]*X[g] ), bf16 rows.
// No LDS, no barriers -> 8 waves/SIMD latency hiding. 2 nodes/wave, 32 lanes per
// node (ushort4 = 4 feats). Index-cache: lane l loads slot[o+l]+dinv coalesced;
// gather loop gets (s,d) via __shfl; groups of 8 load into named registers first.
__global__ __launch_bounds__(256) void agg_bf(const unsigned short* __restrict__ Xh,
        const uint32_t* __restrict__ offs, const uint32_t* __restrict__ cnt,
        const uint32_t* __restrict__ slot, const float* __restrict__ dinv,
        unsigned short* __restrict__ OUT){
    int wgid = blockIdx.x * 4 + (threadIdx.x >> 6);   // global wave id
    int lane = threadIdx.x & 63;
    int h = lane >> 5, l = lane & 31;
    int g = wgid * 2 + h;                             // node id (grid sized exactly)
    const ushort4* X4 = (const ushort4*)Xh;
    uint32_t o = offs[g], c = cnt[g];
    float ax = 0.f, ay = 0.f, az = 0.f, aw = 0.f;
    #pragma unroll 1
    for (uint32_t base = 0; base < c; base += 32){
        int rem = (int)(c - base); if (rem > 32) rem = 32;
        uint32_t idx = 0u; float ds = 0.f;
        if (l < rem){
            idx = slot[o + base + (uint32_t)l];
            ds = dinv[idx];
        }
        int groups = (rem + 7) >> 3;
        #pragma unroll 1
        for (int gq = 0; gq < groups; gq++){
            int eb = gq * 8;
            ushort4 v[8]; float d[8];
            #pragma unroll
            for (int j = 0; j < 8; j++){
                uint32_t s = (uint32_t)__shfl((int)idx, eb + j, 32);
                d[j] = __shfl(ds, eb + j, 32);
                v[j] = X4[(size_t)s * 32 + l];
            }
            #pragma unroll
            for (int j = 0; j < 8; j++){
                ax += d[j] * bf2f(v[j].x);
                ay += d[j] * bf2f(v[j].y);
                az += d[j] * bf2f(v[j].z);
                aw += d[j] * bf2f(v[j].w);
            }
        }
    }
    float dd = dinv[g];
    ushort4 sv = X4[(size_t)g * 32 + l];
    ushort4 r = { f2bf(dd * (ax + dd * bf2f(sv.x))),
                  f2bf(dd * (ay + dd * bf2f(sv.y))),
                  f2bf(dd * (az + dd * bf2f(sv.z))),
                  f2bf(dd * (aw + dd * bf2f(sv.w))) };
    ((ushort4*)OUT)[(size_t)g * 32 + l] = r;
}

// ---------------------------------------------------------------- MFMA GEMM layer 1
// OUT = bf16( relu( Xagg @ W1 + b1 ) ). 4 waves/block, wave = 16 rows x 128 cols.
// Software pipeline with named register banks; B frags are single coalesced 1KB
// loads from fragment-order Wtf (L1/L2 resident).
__global__ __launch_bounds__(256) void gemm_mfma_l1(const unsigned short* __restrict__ Xagg,
        const unsigned short* __restrict__ Wtf, const float* __restrict__ bias,
        unsigned short* __restrict__ OUT){
    int tid = threadIdx.x;
    int wid = tid >> 6, l = tid & 63;
    int lm = l & 15, lk = l >> 4;
    int rw = blockIdx.x * 64 + wid * 16;            // wave's first row
    int ra = rw + lm; ra = ra < N_NODES ? ra : N_NODES - 1;
    const bf16x8* Wv = (const bf16x8*)Wtf;          // frag index = (cb*4+step)*64 + l

    f32x4 acc[8] = {};
    bf16x8 aA, aB, bA[8], bB[8];

    aA = *(const bf16x8*)(Xagg + (size_t)ra * 128 + lk * 8);
    #pragma unroll
    for (int cb = 0; cb < 8; cb++) bA[cb] = Wv[(size_t)(cb * 4 + 0) * 64 + l];

    aB = *(const bf16x8*)(Xagg + (size_t)ra * 128 + 32 + lk * 8);
    #pragma unroll
    for (int cb = 0; cb < 8; cb++) bB[cb] = Wv[(size_t)(cb * 4 + 1) * 64 + l];
    #pragma unroll
    for (int cb = 0; cb < 8; cb++)
        acc[cb] = __builtin_amdgcn_mfma_f32_16x16x32_bf16(aA, bA[cb], acc[cb], 0, 0, 0);

    aA = *(const bf16x8*)(Xagg + (size_t)ra * 128 + 64 + lk * 8);
    #pragma unroll
    for (int cb = 0; cb < 8; cb++) bA[cb] = Wv[(size_t)(cb * 4 + 2) * 64 + l];
    #pragma unroll
    for (int cb = 0; cb < 8; cb++)
        acc[cb] = __builtin_amdgcn_mfma_f32_16x16x32_bf16(aB, bB[cb], acc[cb], 0, 0, 0);

    aB = *(const bf16x8*)(Xagg + (size_t)ra * 128 + 96 + lk * 8);
    #pragma unroll
    for (int cb = 0; cb < 8; cb++) bB[cb] = Wv[(size_t)(cb * 4 + 3) * 64 + l];
    #pragma unroll
    for (int cb = 0; cb < 8; cb++)
        acc[cb] = __builtin_amdgcn_mfma_f32_16x16x32_bf16(aA, bA[cb], acc[cb], 0, 0, 0);

    #pragma unroll
    for (int cb = 0; cb < 8; cb++)
        acc[cb] = __builtin_amdgcn_mfma_f32_16x16x32_bf16(aB, bB[cb], acc[cb], 0, 0, 0);

    #pragma unroll
    for (int cb = 0; cb < 8; cb++){
        int col = cb * 16 + lm;
        float bs = bias[col];
        #pragma unroll
        for (int i = 0; i < 4; i++){
            int row = rw + lk * 4 + i;
            if (row < N_NODES)
                OUT[(size_t)row * 128 + col] = f2bf(fmaxf(acc[cb][i] + bs, 0.f));
        }
    }
}

// ---------------------------------------------------------------- MFMA GEMM layer 2
// OUT = Aagg @ W2 + b2 (fp32, 40 cols; Wtf2 padded to 48 cols with zeros).
__global__ __launch_bounds__(256) void gemm_mfma_l2(const unsigned short* __restrict__ Aagg,
        const unsigned short* __restrict__ Wtf, const float* __restrict__ bias,
        float* __restrict__ OUT){
    int tid = threadIdx.x;
    int wid = tid >> 6, l = tid & 63;
    int lm = l & 15, lk = l >> 4;
    int rw = blockIdx.x * 64 + wid * 16;
    int ra = rw + lm; ra = ra < N_NODES ? ra : N_NODES - 1;
    const bf16x8* Wv = (const bf16x8*)Wtf;

    f32x4 acc[3] = {};
    bf16x8 aA, aB, bA[3], bB[3];

    aA = *(const bf16x8*)(Aagg + (size_t)ra * 128 + lk * 8);
    #pragma unroll
    for (int cb = 0; cb < 3; cb++) bA[cb] = Wv[(size_t)(cb * 4 + 0) * 64 + l];

    aB = *(const bf16x8*)(Aagg + (size_t)ra * 128 + 32 + lk * 8);
    #pragma unroll
    for (int cb = 0; cb < 3; cb++) bB[cb] = Wv[(size_t)(cb * 4 + 1) * 64 + l];
    #pragma unroll
    for (int cb = 0; cb < 3; cb++)
        acc[cb] = __builtin_amdgcn_mfma_f32_16x16x32_bf16(aA, bA[cb], acc[cb], 0, 0, 0);

    aA = *(const bf16x8*)(Aagg + (size_t)ra * 128 + 64 + lk * 8);
    #pragma unroll
    for (int cb = 0; cb < 3; cb++) bA[cb] = Wv[(size_t)(cb * 4 + 2) * 64 + l];
    #pragma unroll
    for (int cb = 0; cb < 3; cb++)
        acc[cb] = __builtin_amdgcn_mfma_f32_16x16x32_bf16(aB, bB[cb], acc[cb], 0, 0, 0);

    aB = *(const bf16x8*)(Aagg + (size_t)ra * 128 + 96 + lk * 8);
    #pragma unroll
    for (int cb = 0; cb < 3; cb++) bB[cb] = Wv[(size_t)(cb * 4 + 3) * 64 + l];
    #pragma unroll
    for (int cb = 0; cb < 3; cb++)
        acc[cb] = __builtin_amdgcn_mfma_f32_16x16x32_bf16(aA, bA[cb], acc[cb], 0, 0, 0);

    #pragma unroll
    for (int cb = 0; cb < 3; cb++)
        acc[cb] = __builtin_amdgcn_mfma_f32_16x16x32_bf16(aB, bB[cb], acc[cb], 0, 0, 0);

    #pragma unroll
    for (int cb = 0; cb < 3; cb++){
        int col = cb * 16 + lm;
        if (col < 40){
            float bs = bias[col];
            #pragma unroll
            for (int i = 0; i < 4; i++){
                int row = rw + lk * 4 + i;
                if (row < N_NODES) OUT[(size_t)row * 40 + col] = acc[cb][i] + bs;
            }
        }
    }
}

// ---------------------------------------------------------------- launch
extern "C" void kernel_launch(void* const* d_in, const int* in_sizes, int n_in,
                              void* d_out, int out_size, void* d_ws, size_t ws_size,
                              hipStream_t stream) {
    const float* x   = (const float*)d_in[0];
    const int*   ei  = (const int*)d_in[1];      // int32 (harness converts integer inputs)
    const float* W1  = (const float*)d_in[2];
    const float* b1  = (const float*)d_in[3];
    const float* W2  = (const float*)d_in[4];
    const float* b2  = (const float*)d_in[5];
    float*       out = (float*)d_out;

    const int N = N_NODES;
    const int E = in_sizes[1] / 2;
    const int* src = ei;
    const int* dst = ei + E;

    // workspace carve-up (512B-aligned). ~84 MiB total (Xh aliased as Aagg2).
    char* ws = (char*)d_ws;
    size_t o = 0;
    auto alloc = [&](size_t bytes) -> char* {
        char* p = ws + o;
        o += (bytes + 511) & ~(size_t)511;
        return p;
    };
    uint32_t*       hist  = (uint32_t*)alloc((size_t)NBP * 4);
    uint32_t*       bbase = (uint32_t*)alloc((size_t)NBP * 4);
    uint32_t*       bcur  = (uint32_t*)alloc((size_t)NBP * 4);
    uint32_t*       ebuf  = (uint32_t*)alloc((size_t)E * 4);
    uint32_t*       offs  = (uint32_t*)alloc((size_t)N * 4);
    uint32_t*       cnt   = (uint32_t*)alloc((size_t)N * 4);
    uint32_t*       slot  = (uint32_t*)alloc((size_t)E * 4);
    float*          dinv  = (float*)alloc((size_t)N * 4);
    unsigned short* Wtf1  = (unsigned short*)alloc((size_t)8 * 4 * 64 * 8 * 2);  // 32 KB
    unsigned short* Wtf2  = (unsigned short*)alloc((size_t)3 * 4 * 64 * 8 * 2);  // 12 KB
    unsigned short* Xh    = (unsigned short*)alloc((size_t)N * 128 * 2);  // bf16 x; later Aagg2
    unsigned short* Xagg  = (unsigned short*)alloc((size_t)N * 128 * 2);  // aggregated x (bf16)
    unsigned short* Ah    = (unsigned short*)alloc((size_t)N * 128 * 2);  // layer-1 act (bf16)
    unsigned short* Aagg2 = Xh;   // Xh dead after agg1; reuse

    const int n4 = N * 128 / 4;
    const int nblk_agg = N / 8;                   // 12500
    const int nblk_gemm = (N + 63) / 64;          // 1563
    const int nblk_edge = (E + 12799) / 12800;    // 50

    // --- CSR build (bucketed, dense writes) + bf16 conversions ---
    zero_u32<<<(NBP + 255) / 256, 256, 0, stream>>>(hist, NBP);
    to_bf16<<<(n4 + 255) / 256, 256, 0, stream>>>(x, Xh, n4);
    transpose_w_frag<<<64, 256, 0, stream>>>(W1, Wtf1, 128, 8 * 4 * 64 * 8);
    transpose_w_frag<<<24, 256, 0, stream>>>(W2, Wtf2, 40, 3 * 4 * 64 * 8);
    bucket_hist<<<nblk_edge, 1024, 0, stream>>>(dst, hist, E);
    scan_buckets<<<1, 256, 0, stream>>>(hist, bbase, bcur);
    bucket_scatter<<<nblk_edge, 1024, 0, stream>>>(src, dst, bcur, ebuf, E);
    bucket_csr<<<NB, 256, 0, stream>>>(hist, bbase, ebuf, offs, cnt, dinv, slot, N);

    // --- layer 1 ---
    agg_bf<<<nblk_agg, 256, 0, stream>>>(Xh, offs, cnt, slot, dinv, Xagg);
    gemm_mfma_l1<<<nblk_gemm, 256, 0, stream>>>(Xagg, Wtf1, b1, Ah);

    // --- layer 2 ---
    agg_bf<<<nblk_agg, 256, 0, stream>>>(Ah, offs, cnt, slot, dinv, Aagg2);
    gemm_mfma_l2<<<nblk_gemm, 256, 0, stream>>>(Aagg2, Wtf2, b2, out);
}